// Round 8
// baseline (128.912 us; speedup 1.0000x reference)
//
#include <hip/hip_runtime.h>
#include <hip/hip_fp16.h>
#include <stdint.h>

typedef _Float16 f16;
typedef __attribute__((ext_vector_type(8))) _Float16 f16x8;
typedef __attribute__((ext_vector_type(4))) _Float16 f16x4;
typedef __attribute__((ext_vector_type(4))) float f32x4;

#define SEQ 2048
#define DIM 1024
#define NBATCH 2
#define MTOT 4096  // NBATCH*SEQ

__global__ void fill_kernel(float* p, float v, int n){
  int i = blockIdx.x * 256 + threadIdx.x;
  if (i < n) p[i] = v;
}

// Merged fp32->fp16 convert + rowacc zero-init.
// blocks 0..4095 -> x, 4096..8191 -> weights, 8192 -> zero rowacc.
__global__ void cvt_all(const float* __restrict__ x, const float* __restrict__ Wq,
                        const float* __restrict__ Wk, const float* __restrict__ Wv,
                        const float* __restrict__ Wo,
                        f16* __restrict__ x16, f16* __restrict__ Wcat, f16* __restrict__ Wo16,
                        float* __restrict__ rowacc){
  int b = blockIdx.x;
  if (b == 8192){
    float4 z = {0.f, 0.f, 0.f, 0.f};
#pragma unroll
    for (int i = 0; i < 4; i++) ((float4*)rowacc)[threadIdx.x + i * 256] = z;
    return;
  }
  const float* src; f16* dst; int i;
  if (b < 4096){
    src = x; dst = x16; i = b * 256 + threadIdx.x;
  } else {
    int t = (b - 4096) >> 10;
    i = ((b - 4096) & 1023) * 256 + threadIdx.x;
    src = t == 0 ? Wq : t == 1 ? Wk : t == 2 ? Wv : Wo;
    dst = (t == 3) ? Wo16 : Wcat + (size_t)t * DIM * DIM;
  }
  float4 v = ((const float4*)src)[i];
  ((f16x4*)dst)[i] = (f16x4){(f16)v.x, (f16)v.y, (f16)v.z, (f16)v.w};
}

#define GLOAD16(SRC, DST) __builtin_amdgcn_global_load_lds( \
    (__attribute__((address_space(1))) void*)(SRC), \
    (__attribute__((address_space(3))) void*)(DST), 16, 0, 0)

// theta -> unnormalized exp (shift 10, clamp 11). x->-inf: e1=inf -> sg=0, th=-1.
__device__ __forceinline__ float theta_exp(float v){
  const float e1 = __expf(-v);
  const float sg = 1.f / (1.f + e1);
  const float e2 = e1 * e1;             // e^{-2x}
  const float th = 2.f / (1.f + e2) - 1.f;
  const float theta = 0.5f + 0.2f * sg + 0.15f * th + 0.1f * fmaxf(v, 0.f);
  return __expf(fminf(theta - 10.f, 11.f));
}

// ---------------------------------------------------------------------------
// qkv: 256-thr 128x128 tile, BK=64, single-buffer, 2 barriers/tile (R5/R7
// proven). XOR swizzle: LDS[r][cb] = G[r][cb^(r&7)], linear gload_lds dest +
// pre-swizzled source; reads apply same XOR (0 conflicts measured).
// grid (32,24): col<2048 -> qkcat(+bq/bk), col>=2048 -> vbuf row-major (+bv).
// ---------------------------------------------------------------------------
__global__ __launch_bounds__(256, 3)
void gemm_qkv(const f16* __restrict__ A0, const f16* __restrict__ B0,
              f16* __restrict__ O0, f16* __restrict__ O1,
              const float* __restrict__ c0, const float* __restrict__ c1,
              const float* __restrict__ c2)
{
  __shared__ __align__(16) f16 As[8192];   // 128 x 64 f16
  __shared__ __align__(16) f16 Bs[8192];
  const int tid  = threadIdx.x;
  const int lane = tid & 63;
  const int wid  = tid >> 6;
  const int bm = blockIdx.x, bn = blockIdx.y;

  const int s_r  = tid >> 3;            // 0..31
  const int s_cb = (tid & 7) ^ (s_r & 7);
  const f16* Ab = A0 + (long)(bm * 128 + s_r) * DIM + s_cb * 8;
  const f16* Bb = B0 + (long)(bn * 128 + s_r) * DIM + s_cb * 8;

  const int l15 = lane & 15, l7 = lane & 7, lhi = lane >> 4;
  const int wrow = (wid >> 1) * 64;
  const int wcol = (wid & 1) * 64;
  const int ar = (wrow + l15) * 64;
  const int br = (wcol + l15) * 64;
  const int cb0 = ((0 + lhi) ^ l7) * 8;
  const int cb1 = ((4 + lhi) ^ l7) * 8;

  f32x4 acc[4][4] = {};

  for (int t = 0; t < 16; ++t){
    __syncthreads();
    GLOAD16(Ab + (long)t*64,                  &As[       tid*8]);
    GLOAD16(Ab + (long)t*64 + (long)32 * DIM, &As[2048 + tid*8]);
    GLOAD16(Ab + (long)t*64 + (long)64 * DIM, &As[4096 + tid*8]);
    GLOAD16(Ab + (long)t*64 + (long)96 * DIM, &As[6144 + tid*8]);
    GLOAD16(Bb + (long)t*64,                  &Bs[       tid*8]);
    GLOAD16(Bb + (long)t*64 + (long)32 * DIM, &Bs[2048 + tid*8]);
    GLOAD16(Bb + (long)t*64 + (long)64 * DIM, &Bs[4096 + tid*8]);
    GLOAD16(Bb + (long)t*64 + (long)96 * DIM, &Bs[6144 + tid*8]);
    __syncthreads();
    f16x8 af[4], bf[4];
#pragma unroll
    for (int i = 0; i < 4; i++) af[i] = *(const f16x8*)&As[ar + i * 1024 + cb0];
#pragma unroll
    for (int j = 0; j < 4; j++) bf[j] = *(const f16x8*)&Bs[br + j * 1024 + cb0];
#pragma unroll
    for (int i = 0; i < 4; i++)
#pragma unroll
      for (int j = 0; j < 4; j++)
        acc[i][j] = __builtin_amdgcn_mfma_f32_16x16x32_f16(af[i], bf[j], acc[i][j], 0, 0, 0);
#pragma unroll
    for (int i = 0; i < 4; i++) af[i] = *(const f16x8*)&As[ar + i * 1024 + cb1];
#pragma unroll
    for (int j = 0; j < 4; j++) bf[j] = *(const f16x8*)&Bs[br + j * 1024 + cb1];
#pragma unroll
    for (int i = 0; i < 4; i++)
#pragma unroll
      for (int j = 0; j < 4; j++)
        acc[i][j] = __builtin_amdgcn_mfma_f32_16x16x32_f16(af[i], bf[j], acc[i][j], 0, 0, 0);
  }

  const int cc = l15;
  const int rr = lhi * 4;
#pragma unroll
  for (int i = 0; i < 4; i++)
#pragma unroll
    for (int j = 0; j < 4; j++){
      const int col = bn * 128 + wcol + j * 16 + cc;
      if (col < 2048){
        const float badd = (col < 1024) ? c0[col] : c1[col - 1024];
#pragma unroll
        for (int r = 0; r < 4; r++){
          const int row = bm * 128 + wrow + i * 16 + rr + r;
          O0[(long)row * 2048 + col] = (f16)(acc[i][j][r] + badd);
        }
      } else {
        const int dcol = col - 2048;
        const float badd = c2[dcol];
#pragma unroll
        for (int r = 0; r < 4; r++){
          const int row = bm * 128 + wrow + i * 16 + rr + r;
          O1[(long)row * DIM + dcol] = (f16)(acc[i][j][r] + badd);
        }
      }
    }
}

// ---------------------------------------------------------------------------
// Merged qk + vWo, grid 1280 linear = EXACTLY 5 blocks/CU (5 x 32 KiB LDS =
// 160 KiB), 20 waves/CU = 5/SIMD. Per-CU load balanced: 4 light qk blocks +
// 1 heavy vWo block each (4*16.8 + 33.5 MF).
//   blocks 0..1023:    qk, tile 128x64 (bm 16 x bn 32 x bz 2). A=q, B=k from
//                      qkcat (ld 2048). Epilogue: P=theta_exp -> Pbuf,
//                      rowsum atomicAdd -> rowacc.
//   blocks 1024..1279: vWo, tile 128x128 (R7 geometry). A=vbuf, B=Wo16.
//                      Epilogue: transposed f16x4 scatter -> vWoT[b][e][t].
// Same BK=64 single-buffer 2-barrier K-loop + XOR swizzle in both paths.
// ---------------------------------------------------------------------------
__global__ __launch_bounds__(256, 5)
void gemm_merged(const f16* __restrict__ qkcat, const f16* __restrict__ vbuf,
                 const f16* __restrict__ Wo16,
                 f16* __restrict__ Pbuf, f16* __restrict__ vWoT,
                 float* __restrict__ rowacc)
{
  __shared__ __align__(16) f16 As[8192];
  __shared__ __align__(16) f16 Bs[8192];
  const int tid  = threadIdx.x;
  const int lane = tid & 63;
  const int wid  = tid >> 6;
  const int l15 = lane & 15, l7 = lane & 7, lhi = lane >> 4;
  const int s_r  = tid >> 3;
  const int s_cb = (tid & 7) ^ (s_r & 7);
  const int cb0 = ((0 + lhi) ^ l7) * 8;
  const int cb1 = ((4 + lhi) ^ l7) * 8;
  const int cc = l15, rr = lhi * 4;
  const int r = blockIdx.x;

  if (r < 1024){
    // ---------------- qk path: tile 128x64 ----------------
    const int bz = r >> 9, q = r & 511, bm = q >> 5, bn = q & 31;
    const f16* Ag = qkcat + (long)bz * SEQ * 2048;          // q rows
    const f16* Bg = qkcat + DIM + (long)bz * SEQ * 2048;    // k rows
    const f16* Ab = Ag + (long)(bm * 128 + s_r) * 2048 + s_cb * 8;
    const f16* Bb = Bg + (long)(bn * 64  + s_r) * 2048 + s_cb * 8;

    const int wrow = (wid >> 1) * 64;     // {0,64}
    const int wcol = (wid & 1) * 32;      // {0,32}
    const int ar = (wrow + l15) * 64;
    const int br = (wcol + l15) * 64;

    f32x4 acc[4][2] = {};

    for (int t = 0; t < 16; ++t){
      __syncthreads();
      GLOAD16(Ab + (long)t*64,                   &As[       tid*8]);
      GLOAD16(Ab + (long)t*64 + (long)32 * 2048, &As[2048 + tid*8]);
      GLOAD16(Ab + (long)t*64 + (long)64 * 2048, &As[4096 + tid*8]);
      GLOAD16(Ab + (long)t*64 + (long)96 * 2048, &As[6144 + tid*8]);
      GLOAD16(Bb + (long)t*64,                   &Bs[       tid*8]);
      GLOAD16(Bb + (long)t*64 + (long)32 * 2048, &Bs[2048 + tid*8]);
      __syncthreads();
      f16x8 af[4], bf[2];
#pragma unroll
      for (int i = 0; i < 4; i++) af[i] = *(const f16x8*)&As[ar + i * 1024 + cb0];
#pragma unroll
      for (int j = 0; j < 2; j++) bf[j] = *(const f16x8*)&Bs[br + j * 1024 + cb0];
#pragma unroll
      for (int i = 0; i < 4; i++)
#pragma unroll
        for (int j = 0; j < 2; j++)
          acc[i][j] = __builtin_amdgcn_mfma_f32_16x16x32_f16(af[i], bf[j], acc[i][j], 0, 0, 0);
#pragma unroll
      for (int i = 0; i < 4; i++) af[i] = *(const f16x8*)&As[ar + i * 1024 + cb1];
#pragma unroll
      for (int j = 0; j < 2; j++) bf[j] = *(const f16x8*)&Bs[br + j * 1024 + cb1];
#pragma unroll
      for (int i = 0; i < 4; i++)
#pragma unroll
        for (int j = 0; j < 2; j++)
          acc[i][j] = __builtin_amdgcn_mfma_f32_16x16x32_f16(af[i], bf[j], acc[i][j], 0, 0, 0);
    }

#pragma unroll
    for (int i = 0; i < 4; i++)
#pragma unroll
      for (int rq = 0; rq < 4; rq++){
        const int row = bm * 128 + wrow + i * 16 + rr + rq;
        float rs = 0.f;
#pragma unroll
        for (int j = 0; j < 2; j++){
          const int col = bn * 64 + wcol + j * 16 + cc;
          const float P = theta_exp(acc[i][j][rq]);
          Pbuf[(long)bz * SEQ * SEQ + (long)row * SEQ + col] = (f16)P;
          rs += P;
        }
        rs += __shfl_xor(rs, 1, 64);
        rs += __shfl_xor(rs, 2, 64);
        rs += __shfl_xor(rs, 4, 64);
        rs += __shfl_xor(rs, 8, 64);
        if (cc == 0) atomicAdd(&rowacc[bz * SEQ + row], rs);
      }
  } else {
    // ---------------- vWo path: tile 128x128 ----------------
    const int q = r - 1024;
    const int bz = q >> 7, qq = q & 127, bm = qq & 15, bn = qq >> 4;
    const f16* Ag = vbuf + (long)bz * SEQ * DIM;
    const f16* Ab = Ag + (long)(bm * 128 + s_r) * DIM + s_cb * 8;
    const f16* Bb = Wo16 + (long)(bn * 128 + s_r) * DIM + s_cb * 8;

    const int wrow = (wid >> 1) * 64;
    const int wcol = (wid & 1) * 64;
    const int ar = (wrow + l15) * 64;
    const int br = (wcol + l15) * 64;

    f32x4 acc[4][4] = {};

    for (int t = 0; t < 16; ++t){
      __syncthreads();
      GLOAD16(Ab + (long)t*64,                  &As[       tid*8]);
      GLOAD16(Ab + (long)t*64 + (long)32 * DIM, &As[2048 + tid*8]);
      GLOAD16(Ab + (long)t*64 + (long)64 * DIM, &As[4096 + tid*8]);
      GLOAD16(Ab + (long)t*64 + (long)96 * DIM, &As[6144 + tid*8]);
      GLOAD16(Bb + (long)t*64,                  &Bs[       tid*8]);
      GLOAD16(Bb + (long)t*64 + (long)32 * DIM, &Bs[2048 + tid*8]);
      GLOAD16(Bb + (long)t*64 + (long)64 * DIM, &Bs[4096 + tid*8]);
      GLOAD16(Bb + (long)t*64 + (long)96 * DIM, &Bs[6144 + tid*8]);
      __syncthreads();
      f16x8 af[4], bf[4];
#pragma unroll
      for (int i = 0; i < 4; i++) af[i] = *(const f16x8*)&As[ar + i * 1024 + cb0];
#pragma unroll
      for (int j = 0; j < 4; j++) bf[j] = *(const f16x8*)&Bs[br + j * 1024 + cb0];
#pragma unroll
      for (int i = 0; i < 4; i++)
#pragma unroll
        for (int j = 0; j < 4; j++)
          acc[i][j] = __builtin_amdgcn_mfma_f32_16x16x32_f16(af[i], bf[j], acc[i][j], 0, 0, 0);
#pragma unroll
      for (int i = 0; i < 4; i++) af[i] = *(const f16x8*)&As[ar + i * 1024 + cb1];
#pragma unroll
      for (int j = 0; j < 4; j++) bf[j] = *(const f16x8*)&Bs[br + j * 1024 + cb1];
#pragma unroll
      for (int i = 0; i < 4; i++)
#pragma unroll
        for (int j = 0; j < 4; j++)
          acc[i][j] = __builtin_amdgcn_mfma_f32_16x16x32_f16(af[i], bf[j], acc[i][j], 0, 0, 0);
    }

#pragma unroll
    for (int i = 0; i < 4; i++)
#pragma unroll
      for (int j = 0; j < 4; j++){
        const int col = bn * 128 + wcol + j * 16 + cc;       // e
        const int row0 = bm * 128 + wrow + i * 16 + rr;      // t (4 consecutive)
        f16x4 pk = {(f16)acc[i][j][0], (f16)acc[i][j][1],
                    (f16)acc[i][j][2], (f16)acc[i][j][3]};
        *(f16x4*)&vWoT[(long)bz * DIM * SEQ + (long)col * SEQ + row0] = pk;
      }
  }
}

// ---------------------------------------------------------------------------
// Final GEMM split-K=2: psum[kh] = P[:, kh*1024:+1024] @ vWoT[:, kh*1024:+1024]^T
// grid (16,8,4) z = bz*2+kh -> 1024 blocks = 4/CU = 4 waves/SIMD. fp32 partials
// (values reach ~1e5 -> must not be fp16). 128x128 tile, NT=16.
// ---------------------------------------------------------------------------
__global__ __launch_bounds__(256, 4)
void gemm_final(const f16* __restrict__ Pb, const f16* __restrict__ Vw,
                float* __restrict__ psum)
{
  __shared__ __align__(16) f16 As[8192];
  __shared__ __align__(16) f16 Bs[8192];
  const int tid  = threadIdx.x;
  const int lane = tid & 63;
  const int wid  = tid >> 6;
  const int bm = blockIdx.x, bn = blockIdx.y;
  const int bz = blockIdx.z >> 1, kh = blockIdx.z & 1;

  const f16* Ag = Pb + (long)bz * SEQ * SEQ + (long)kh * 1024;
  const f16* Bg = Vw + (long)bz * DIM * SEQ + (long)kh * 1024;

  const int s_r  = tid >> 3;
  const int s_cb = (tid & 7) ^ (s_r & 7);
  const f16* Ab = Ag + (long)(bm * 128 + s_r) * 2048 + s_cb * 8;
  const f16* Bb = Bg + (long)(bn * 128 + s_r) * 2048 + s_cb * 8;

  const int l15 = lane & 15, l7 = lane & 7, lhi = lane >> 4;
  const int wrow = (wid >> 1) * 64;
  const int wcol = (wid & 1) * 64;
  const int ar = (wrow + l15) * 64;
  const int br = (wcol + l15) * 64;
  const int cb0 = ((0 + lhi) ^ l7) * 8;
  const int cb1 = ((4 + lhi) ^ l7) * 8;

  f32x4 acc[4][4] = {};

  for (int t = 0; t < 16; ++t){
    __syncthreads();
    GLOAD16(Ab + (long)t*64,                   &As[       tid*8]);
    GLOAD16(Ab + (long)t*64 + (long)32 * 2048, &As[2048 + tid*8]);
    GLOAD16(Ab + (long)t*64 + (long)64 * 2048, &As[4096 + tid*8]);
    GLOAD16(Ab + (long)t*64 + (long)96 * 2048, &As[6144 + tid*8]);
    GLOAD16(Bb + (long)t*64,                   &Bs[       tid*8]);
    GLOAD16(Bb + (long)t*64 + (long)32 * 2048, &Bs[2048 + tid*8]);
    GLOAD16(Bb + (long)t*64 + (long)64 * 2048, &Bs[4096 + tid*8]);
    GLOAD16(Bb + (long)t*64 + (long)96 * 2048, &Bs[6144 + tid*8]);
    __syncthreads();
    f16x8 af[4], bf[4];
#pragma unroll
    for (int i = 0; i < 4; i++) af[i] = *(const f16x8*)&As[ar + i * 1024 + cb0];
#pragma unroll
    for (int j = 0; j < 4; j++) bf[j] = *(const f16x8*)&Bs[br + j * 1024 + cb0];
#pragma unroll
    for (int i = 0; i < 4; i++)
#pragma unroll
      for (int j = 0; j < 4; j++)
        acc[i][j] = __builtin_amdgcn_mfma_f32_16x16x32_f16(af[i], bf[j], acc[i][j], 0, 0, 0);
#pragma unroll
    for (int i = 0; i < 4; i++) af[i] = *(const f16x8*)&As[ar + i * 1024 + cb1];
#pragma unroll
    for (int j = 0; j < 4; j++) bf[j] = *(const f16x8*)&Bs[br + j * 1024 + cb1];
#pragma unroll
    for (int i = 0; i < 4; i++)
#pragma unroll
      for (int j = 0; j < 4; j++)
        acc[i][j] = __builtin_amdgcn_mfma_f32_16x16x32_f16(af[i], bf[j], acc[i][j], 0, 0, 0);
  }

  const int cc = l15;
  const int rr = lhi * 4;
  float* Po = psum + (long)kh * MTOT * DIM + (long)bz * SEQ * DIM;
#pragma unroll
  for (int i = 0; i < 4; i++)
#pragma unroll
    for (int j = 0; j < 4; j++){
      const int col = bn * 128 + wcol + j * 16 + cc;
#pragma unroll
      for (int r = 0; r < 4; r++){
        const int row = bm * 128 + wrow + i * 16 + rr + r;
        Po[(long)row * DIM + col] = acc[i][j][r];
      }
    }
}

// out = (psum0 + psum1) / rowacc[row] + bo[col], fp32, float4-vectorized.
__global__ __launch_bounds__(256)
void combine_kernel(const float* __restrict__ psum, const float* __restrict__ rowacc,
                    const float* __restrict__ bo, float* __restrict__ out)
{
  const long i = (long)blockIdx.x * 256 + threadIdx.x;   // float4 index
  const int row = (int)(i >> 8);
  const int c4  = (int)(i & 255);
  float4 a = ((const float4*)psum)[i];
  float4 b = ((const float4*)(psum + (size_t)MTOT * DIM))[i];
  float4 bb = ((const float4*)bo)[c4];
  const float inv = 1.f / rowacc[row];
  float4 o;
  o.x = (a.x + b.x) * inv + bb.x;
  o.y = (a.y + b.y) * inv + bb.y;
  o.z = (a.z + b.z) * inv + bb.z;
  o.w = (a.w + b.w) * inv + bb.w;
  ((float4*)out)[i] = o;
}

extern "C" void kernel_launch(void* const* d_in, const int* in_sizes, int n_in,
                              void* d_out, int out_size, void* d_ws, size_t ws_size,
                              hipStream_t stream){
  const float* x  = (const float*)d_in[0];
  const float* Wq = (const float*)d_in[1];
  const float* bq = (const float*)d_in[2];
  const float* Wk = (const float*)d_in[3];
  const float* bk = (const float*)d_in[4];
  const float* Wv = (const float*)d_in[5];
  const float* bv = (const float*)d_in[6];
  const float* Wo = (const float*)d_in[7];
  const float* bo = (const float*)d_in[8];
  float* out = (float*)d_out;

  char* ws = (char*)d_ws;
  size_t off = 0;
  auto alloc = [&](size_t bytes) -> char* {
    char* p = ws + off; off += (bytes + 255) & ~(size_t)255; return p;
  };

  f16* x16     = (f16*)alloc(2ull * MTOT * DIM);          // 8 MB
  f16* Wcat    = (f16*)alloc(2ull * 3 * DIM * DIM);       // 6 MB  [Wq;Wk;Wv]
  f16* Wo16    = (f16*)alloc(2ull * DIM * DIM);           // 2 MB
  f16* qkcat   = (f16*)alloc(2ull * MTOT * 2 * DIM);      // 16 MB [q|k] per row
  f16* vbuf    = (f16*)alloc(2ull * MTOT * DIM);          // 8 MB  v row-major
  f16* Pbuf    = (f16*)alloc(2ull * NBATCH * SEQ * SEQ);  // 16 MB unnormalized exp
  f16* vWoT    = (f16*)alloc(2ull * NBATCH * DIM * SEQ);  // 8 MB  (v@Wo^T)^T [b][e][t]
  float* rowac = (float*)alloc(4ull * MTOT);              // 16 KB row sums
  float* psum  = (float*)alloc(4ull * 2 * MTOT * DIM);    // 32 MB split-K partials

  if (off > ws_size){
    fill_kernel<<<(out_size + 255) / 256, 256, 0, stream>>>(out, 12345.0f, out_size);
    return;
  }

  cvt_all<<<8193, 256, 0, stream>>>(x, Wq, Wk, Wv, Wo, x16, Wcat, Wo16, rowac);

  // fused [q|k|v] = x @ [Wq;Wk;Wv]^T + bias  (grid 32x24 = 768 blocks, 3/CU)
  gemm_qkv<<<dim3(MTOT / 128, 3 * DIM / 128, 1), 256, 0, stream>>>(
      x16, Wcat, qkcat, vbuf, bq, bk, bv);

  // merged: qk->P(+rowsum) [0..1023, 128x64] and vWo^T [1024..1279, 128x128]
  // 1280 blocks = exactly 5/CU, 20 waves/CU
  gemm_merged<<<1280, 256, 0, stream>>>(qkcat, vbuf, Wo16, Pbuf, vWoT, rowac);

  // split-K=2 final partials (grid 16x8x4 = 1024 blocks, 4/CU)
  gemm_final<<<dim3(SEQ / 128, DIM / 128, 2 * NBATCH), 256, 0, stream>>>(
      Pbuf, vWoT, psum);

  // out = (p0+p1)/rowsum + bo  (4096 blocks, float4)
  combine_kernel<<<MTOT * DIM / 4 / 256, 256, 0, stream>>>(psum, rowac, bo, out);
}

// Round 9
// 127.738 us; speedup vs baseline: 1.0092x; 1.0092x over previous
//
#include <hip/hip_runtime.h>
#include <hip/hip_fp16.h>
#include <stdint.h>

typedef _Float16 f16;
typedef __attribute__((ext_vector_type(8))) _Float16 f16x8;
typedef __attribute__((ext_vector_type(4))) _Float16 f16x4;
typedef __attribute__((ext_vector_type(4))) float f32x4;

#define SEQ 2048
#define DIM 1024
#define NBATCH 2
#define MTOT 4096  // NBATCH*SEQ

__global__ void fill_kernel(float* p, float v, int n){
  int i = blockIdx.x * 256 + threadIdx.x;
  if (i < n) p[i] = v;
}

// Merged setup: fp32->fp16 converts + rowacc zero + out=bias prefill.
// blocks 0..4095 -> x, 4096..8191 -> weights, 8192 -> zero rowacc,
// 8193..12288 -> out[i4] = bias4[i4 & 255]  (4096 blocks)
__global__ void cvt_all(const float* __restrict__ x, const float* __restrict__ Wq,
                        const float* __restrict__ Wk, const float* __restrict__ Wv,
                        const float* __restrict__ Wo, const float* __restrict__ bo,
                        f16* __restrict__ x16, f16* __restrict__ Wcat, f16* __restrict__ Wo16,
                        float* __restrict__ rowacc, float* __restrict__ out){
  int b = blockIdx.x;
  if (b >= 8193){
    const long i = (long)(b - 8193) * 256 + threadIdx.x;   // float4 index
    ((float4*)out)[i] = ((const float4*)bo)[i & 255];
    return;
  }
  if (b == 8192){
    float4 z = {0.f, 0.f, 0.f, 0.f};
#pragma unroll
    for (int i = 0; i < 4; i++) ((float4*)rowacc)[threadIdx.x + i * 256] = z;
    return;
  }
  const float* src; f16* dst; int i;
  if (b < 4096){
    src = x; dst = x16; i = b * 256 + threadIdx.x;
  } else {
    int t = (b - 4096) >> 10;
    i = ((b - 4096) & 1023) * 256 + threadIdx.x;
    src = t == 0 ? Wq : t == 1 ? Wk : t == 2 ? Wv : Wo;
    dst = (t == 3) ? Wo16 : Wcat + (size_t)t * DIM * DIM;
  }
  float4 v = ((const float4*)src)[i];
  ((f16x4*)dst)[i] = (f16x4){(f16)v.x, (f16)v.y, (f16)v.z, (f16)v.w};
}

#define GLOAD16(SRC, DST) __builtin_amdgcn_global_load_lds( \
    (__attribute__((address_space(1))) void*)(SRC), \
    (__attribute__((address_space(3))) void*)(DST), 16, 0, 0)

// theta -> unnormalized exp (shift 10, clamp 11). x->-inf: e1=inf -> sg=0, th=-1.
__device__ __forceinline__ float theta_exp(float v){
  const float e1 = __expf(-v);
  const float sg = 1.f / (1.f + e1);
  const float e2 = e1 * e1;             // e^{-2x}
  const float th = 2.f / (1.f + e2) - 1.f;
  const float theta = 0.5f + 0.2f * sg + 0.15f * th + 0.1f * fmaxf(v, 0.f);
  return __expf(fminf(theta - 10.f, 11.f));
}

// ---------------------------------------------------------------------------
// qkv: 256-thr 128x128 tile, BK=64, single-buffer, 2 barriers/tile. XOR
// swizzle: LDS[r][cb] = G[r][cb^(r&7)], linear gload_lds dest + pre-swizzled
// source; reads apply same XOR (0 conflicts measured R3-R8). K-loop unrolled
// (NT=16) so t*128B folds into load immediates. Grid (32,24) = 768 = 3/CU;
// 768 % 24: each XCD sees only bn ≡ x (mod 8) -> 3 B-panels L2-resident.
// ---------------------------------------------------------------------------
__global__ __launch_bounds__(256, 3)
void gemm_qkv(const f16* __restrict__ A0, const f16* __restrict__ B0,
              f16* __restrict__ O0, f16* __restrict__ O1,
              const float* __restrict__ c0, const float* __restrict__ c1,
              const float* __restrict__ c2)
{
  __shared__ __align__(16) f16 As[8192];   // 128 x 64 f16
  __shared__ __align__(16) f16 Bs[8192];
  const int tid  = threadIdx.x;
  const int lane = tid & 63;
  const int wid  = tid >> 6;
  const int bm = blockIdx.x, bn = blockIdx.y;

  const int s_r  = tid >> 3;            // 0..31
  const int s_cb = (tid & 7) ^ (s_r & 7);
  const f16* Ab = A0 + (long)(bm * 128 + s_r) * DIM + s_cb * 8;
  const f16* Bb = B0 + (long)(bn * 128 + s_r) * DIM + s_cb * 8;

  const int l15 = lane & 15, l7 = lane & 7, lhi = lane >> 4;
  const int wrow = (wid >> 1) * 64;
  const int wcol = (wid & 1) * 64;
  const int ar = (wrow + l15) * 64;
  const int br = (wcol + l15) * 64;
  const int cb0 = ((0 + lhi) ^ l7) * 8;
  const int cb1 = ((4 + lhi) ^ l7) * 8;

  f32x4 acc[4][4] = {};

#pragma unroll
  for (int t = 0; t < 16; ++t){
    __syncthreads();
    GLOAD16(Ab + (long)t*64,                  &As[       tid*8]);
    GLOAD16(Ab + (long)t*64 + (long)32 * DIM, &As[2048 + tid*8]);
    GLOAD16(Ab + (long)t*64 + (long)64 * DIM, &As[4096 + tid*8]);
    GLOAD16(Ab + (long)t*64 + (long)96 * DIM, &As[6144 + tid*8]);
    GLOAD16(Bb + (long)t*64,                  &Bs[       tid*8]);
    GLOAD16(Bb + (long)t*64 + (long)32 * DIM, &Bs[2048 + tid*8]);
    GLOAD16(Bb + (long)t*64 + (long)64 * DIM, &Bs[4096 + tid*8]);
    GLOAD16(Bb + (long)t*64 + (long)96 * DIM, &Bs[6144 + tid*8]);
    __syncthreads();
    f16x8 af[4], bf[4];
#pragma unroll
    for (int i = 0; i < 4; i++) af[i] = *(const f16x8*)&As[ar + i * 1024 + cb0];
#pragma unroll
    for (int j = 0; j < 4; j++) bf[j] = *(const f16x8*)&Bs[br + j * 1024 + cb0];
#pragma unroll
    for (int i = 0; i < 4; i++)
#pragma unroll
      for (int j = 0; j < 4; j++)
        acc[i][j] = __builtin_amdgcn_mfma_f32_16x16x32_f16(af[i], bf[j], acc[i][j], 0, 0, 0);
#pragma unroll
    for (int i = 0; i < 4; i++) af[i] = *(const f16x8*)&As[ar + i * 1024 + cb1];
#pragma unroll
    for (int j = 0; j < 4; j++) bf[j] = *(const f16x8*)&Bs[br + j * 1024 + cb1];
#pragma unroll
    for (int i = 0; i < 4; i++)
#pragma unroll
      for (int j = 0; j < 4; j++)
        acc[i][j] = __builtin_amdgcn_mfma_f32_16x16x32_f16(af[i], bf[j], acc[i][j], 0, 0, 0);
  }

  const int cc = l15;
  const int rr = lhi * 4;
#pragma unroll
  for (int i = 0; i < 4; i++)
#pragma unroll
    for (int j = 0; j < 4; j++){
      const int col = bn * 128 + wcol + j * 16 + cc;
      if (col < 2048){
        const float badd = (col < 1024) ? c0[col] : c1[col - 1024];
#pragma unroll
        for (int r = 0; r < 4; r++){
          const int row = bm * 128 + wrow + i * 16 + rr + r;
          O0[(long)row * 2048 + col] = (f16)(acc[i][j][r] + badd);
        }
      } else {
        const int dcol = col - 2048;
        const float badd = c2[dcol];
#pragma unroll
        for (int r = 0; r < 4; r++){
          const int row = bm * 128 + wrow + i * 16 + rr + r;
          O1[(long)row * DIM + dcol] = (f16)(acc[i][j][r] + badd);
        }
      }
    }
}

// ---------------------------------------------------------------------------
// Merged qk + vWo (R7 proven geometry: both 128x128, 512 + 256 = 768 blocks,
// 3/CU) with XCD-locality remap (assumes block r -> XCD (r%8); if the mapping
// differs it's only a perf heuristic, correctness unaffected):
//   qk (r<512):   x=r&7, i=r>>3; bz=x>>2; bn=(x&3)*4+(i&3); bm=i>>2.
//                 Per XCD: 4 k-panels (1MB) L2-hot; each q-panel read 4x
//                 back-to-back. Epilogue: P=theta_exp -> Pbuf, rowsum atomics.
//   vWo (r>=512): x=rr&7, i=rr>>3; bz=x>>2; bn=(x&3)*2+(i&1); bm=i>>1.
//                 Epilogue: transposed f16x4 scatter -> vWoT[b][e][t].
// ---------------------------------------------------------------------------
__global__ __launch_bounds__(256, 3)
void gemm_merged(const f16* __restrict__ qkcat, const f16* __restrict__ vbuf,
                 const f16* __restrict__ Wo16,
                 f16* __restrict__ Pbuf, f16* __restrict__ vWoT,
                 float* __restrict__ rowacc)
{
  __shared__ __align__(16) f16 As[8192];
  __shared__ __align__(16) f16 Bs[8192];
  const int tid  = threadIdx.x;
  const int lane = tid & 63;
  const int wid  = tid >> 6;
  const int l15 = lane & 15, l7 = lane & 7, lhi = lane >> 4;
  const int s_r  = tid >> 3;
  const int s_cb = (tid & 7) ^ (s_r & 7);
  const int cb0 = ((0 + lhi) ^ l7) * 8;
  const int cb1 = ((4 + lhi) ^ l7) * 8;
  const int cc = l15, rr = lhi * 4;
  const int wrow = (wid >> 1) * 64;
  const int wcol = (wid & 1) * 64;
  const int ar = (wrow + l15) * 64;
  const int br = (wcol + l15) * 64;
  const int r = blockIdx.x;

  if (r < 512){
    // ---------------- qk path: 128x128, ld 2048 ----------------
    const int x = r & 7, i5 = r >> 3;
    const int bz = x >> 2;
    const int bn = (x & 3) * 4 + (i5 & 3);
    const int bm = i5 >> 2;
    const f16* Ab = qkcat + (long)bz * SEQ * 2048 + (long)(bm * 128 + s_r) * 2048 + s_cb * 8;
    const f16* Bb = qkcat + DIM + (long)bz * SEQ * 2048 + (long)(bn * 128 + s_r) * 2048 + s_cb * 8;

    f32x4 acc[4][4] = {};

#pragma unroll
    for (int t = 0; t < 16; ++t){
      __syncthreads();
      GLOAD16(Ab + (long)t*64,                   &As[       tid*8]);
      GLOAD16(Ab + (long)t*64 + (long)32 * 2048, &As[2048 + tid*8]);
      GLOAD16(Ab + (long)t*64 + (long)64 * 2048, &As[4096 + tid*8]);
      GLOAD16(Ab + (long)t*64 + (long)96 * 2048, &As[6144 + tid*8]);
      GLOAD16(Bb + (long)t*64,                   &Bs[       tid*8]);
      GLOAD16(Bb + (long)t*64 + (long)32 * 2048, &Bs[2048 + tid*8]);
      GLOAD16(Bb + (long)t*64 + (long)64 * 2048, &Bs[4096 + tid*8]);
      GLOAD16(Bb + (long)t*64 + (long)96 * 2048, &Bs[6144 + tid*8]);
      __syncthreads();
      f16x8 af[4], bf[4];
#pragma unroll
      for (int i = 0; i < 4; i++) af[i] = *(const f16x8*)&As[ar + i * 1024 + cb0];
#pragma unroll
      for (int j = 0; j < 4; j++) bf[j] = *(const f16x8*)&Bs[br + j * 1024 + cb0];
#pragma unroll
      for (int i = 0; i < 4; i++)
#pragma unroll
        for (int j = 0; j < 4; j++)
          acc[i][j] = __builtin_amdgcn_mfma_f32_16x16x32_f16(af[i], bf[j], acc[i][j], 0, 0, 0);
#pragma unroll
      for (int i = 0; i < 4; i++) af[i] = *(const f16x8*)&As[ar + i * 1024 + cb1];
#pragma unroll
      for (int j = 0; j < 4; j++) bf[j] = *(const f16x8*)&Bs[br + j * 1024 + cb1];
#pragma unroll
      for (int i = 0; i < 4; i++)
#pragma unroll
        for (int j = 0; j < 4; j++)
          acc[i][j] = __builtin_amdgcn_mfma_f32_16x16x32_f16(af[i], bf[j], acc[i][j], 0, 0, 0);
    }

#pragma unroll
    for (int i = 0; i < 4; i++)
#pragma unroll
      for (int rq = 0; rq < 4; rq++){
        const int row = bm * 128 + wrow + i * 16 + rr + rq;
        float rs = 0.f;
#pragma unroll
        for (int j = 0; j < 4; j++){
          const int col = bn * 128 + wcol + j * 16 + cc;
          const float P = theta_exp(acc[i][j][rq]);
          Pbuf[(long)bz * SEQ * SEQ + (long)row * SEQ + col] = (f16)P;
          rs += P;
        }
        rs += __shfl_xor(rs, 1, 64);
        rs += __shfl_xor(rs, 2, 64);
        rs += __shfl_xor(rs, 4, 64);
        rs += __shfl_xor(rs, 8, 64);
        if (cc == 0) atomicAdd(&rowacc[bz * SEQ + row], rs);
      }
  } else {
    // ---------------- vWo path: 128x128, ld 1024 ----------------
    const int rr2 = r - 512;
    const int x = rr2 & 7, i5 = rr2 >> 3;
    const int bz = x >> 2;
    const int bn = (x & 3) * 2 + (i5 & 1);
    const int bm = i5 >> 1;
    const f16* Ab = vbuf + (long)bz * SEQ * DIM + (long)(bm * 128 + s_r) * DIM + s_cb * 8;
    const f16* Bb = Wo16 + (long)(bn * 128 + s_r) * DIM + s_cb * 8;

    f32x4 acc[4][4] = {};

#pragma unroll
    for (int t = 0; t < 16; ++t){
      __syncthreads();
      GLOAD16(Ab + (long)t*64,                  &As[       tid*8]);
      GLOAD16(Ab + (long)t*64 + (long)32 * DIM, &As[2048 + tid*8]);
      GLOAD16(Ab + (long)t*64 + (long)64 * DIM, &As[4096 + tid*8]);
      GLOAD16(Ab + (long)t*64 + (long)96 * DIM, &As[6144 + tid*8]);
      GLOAD16(Bb + (long)t*64,                  &Bs[       tid*8]);
      GLOAD16(Bb + (long)t*64 + (long)32 * DIM, &Bs[2048 + tid*8]);
      GLOAD16(Bb + (long)t*64 + (long)64 * DIM, &Bs[4096 + tid*8]);
      GLOAD16(Bb + (long)t*64 + (long)96 * DIM, &Bs[6144 + tid*8]);
      __syncthreads();
      f16x8 af[4], bf[4];
#pragma unroll
      for (int i = 0; i < 4; i++) af[i] = *(const f16x8*)&As[ar + i * 1024 + cb0];
#pragma unroll
      for (int j = 0; j < 4; j++) bf[j] = *(const f16x8*)&Bs[br + j * 1024 + cb0];
#pragma unroll
      for (int i = 0; i < 4; i++)
#pragma unroll
        for (int j = 0; j < 4; j++)
          acc[i][j] = __builtin_amdgcn_mfma_f32_16x16x32_f16(af[i], bf[j], acc[i][j], 0, 0, 0);
#pragma unroll
      for (int i = 0; i < 4; i++) af[i] = *(const f16x8*)&As[ar + i * 1024 + cb1];
#pragma unroll
      for (int j = 0; j < 4; j++) bf[j] = *(const f16x8*)&Bs[br + j * 1024 + cb1];
#pragma unroll
      for (int i = 0; i < 4; i++)
#pragma unroll
        for (int j = 0; j < 4; j++)
          acc[i][j] = __builtin_amdgcn_mfma_f32_16x16x32_f16(af[i], bf[j], acc[i][j], 0, 0, 0);
    }

#pragma unroll
    for (int i = 0; i < 4; i++)
#pragma unroll
      for (int j = 0; j < 4; j++){
        const int col = bn * 128 + wcol + j * 16 + cc;       // e
        const int row0 = bm * 128 + wrow + i * 16 + rr;      // t (4 consecutive)
        f16x4 pk = {(f16)acc[i][j][0], (f16)acc[i][j][1],
                    (f16)acc[i][j][2], (f16)acc[i][j][3]};
        *(f16x4*)&vWoT[(long)bz * DIM * SEQ + (long)col * SEQ + row0] = pk;
      }
  }
}

// ---------------------------------------------------------------------------
// Final split-K=2 (R8-measured 593 TF), 512 blocks = 2/CU, NO psum/combine:
// out was pre-filled with bias; epilogue atomicAdd(acc * 1/rowsum) (2 adds per
// element, native global_atomic_add_f32, no contention).
// XCD remap: x=r&7, i=r>>3; z4=x>>1 (bz=z4>>1, kh=z4&1); bn=(x&1)*4+(i&3);
// bm=i>>2. Per XCD: 4 B-panels (1MB) L2-hot, A-panels read 4x back-to-back.
// ---------------------------------------------------------------------------
__global__ __launch_bounds__(256, 2)
void gemm_final(const f16* __restrict__ Pb, const f16* __restrict__ Vw,
                float* __restrict__ out, const float* __restrict__ rowacc)
{
  __shared__ __align__(16) f16 As[8192];
  __shared__ __align__(16) f16 Bs[8192];
  const int tid  = threadIdx.x;
  const int lane = tid & 63;
  const int wid  = tid >> 6;
  const int r = blockIdx.x;
  const int x = r & 7, i5 = r >> 3;
  const int z4 = x >> 1;
  const int bz = z4 >> 1, kh = z4 & 1;
  const int bn = (x & 1) * 4 + (i5 & 3);
  const int bm = i5 >> 2;

  const f16* Ag = Pb + (long)bz * SEQ * SEQ + (long)kh * 1024;
  const f16* Bg = Vw + (long)bz * DIM * SEQ + (long)kh * 1024;

  const int s_r  = tid >> 3;
  const int s_cb = (tid & 7) ^ (s_r & 7);
  const f16* Ab = Ag + (long)(bm * 128 + s_r) * 2048 + s_cb * 8;
  const f16* Bb = Bg + (long)(bn * 128 + s_r) * 2048 + s_cb * 8;

  const int l15 = lane & 15, l7 = lane & 7, lhi = lane >> 4;
  const int wrow = (wid >> 1) * 64;
  const int wcol = (wid & 1) * 64;
  const int ar = (wrow + l15) * 64;
  const int br = (wcol + l15) * 64;
  const int cb0 = ((0 + lhi) ^ l7) * 8;
  const int cb1 = ((4 + lhi) ^ l7) * 8;

  f32x4 acc[4][4] = {};

#pragma unroll
  for (int t = 0; t < 16; ++t){
    __syncthreads();
    GLOAD16(Ab + (long)t*64,                   &As[       tid*8]);
    GLOAD16(Ab + (long)t*64 + (long)32 * 2048, &As[2048 + tid*8]);
    GLOAD16(Ab + (long)t*64 + (long)64 * 2048, &As[4096 + tid*8]);
    GLOAD16(Ab + (long)t*64 + (long)96 * 2048, &As[6144 + tid*8]);
    GLOAD16(Bb + (long)t*64,                   &Bs[       tid*8]);
    GLOAD16(Bb + (long)t*64 + (long)32 * 2048, &Bs[2048 + tid*8]);
    GLOAD16(Bb + (long)t*64 + (long)64 * 2048, &Bs[4096 + tid*8]);
    GLOAD16(Bb + (long)t*64 + (long)96 * 2048, &Bs[6144 + tid*8]);
    __syncthreads();
    f16x8 af[4], bf[4];
#pragma unroll
    for (int i = 0; i < 4; i++) af[i] = *(const f16x8*)&As[ar + i * 1024 + cb0];
#pragma unroll
    for (int j = 0; j < 4; j++) bf[j] = *(const f16x8*)&Bs[br + j * 1024 + cb0];
#pragma unroll
    for (int i = 0; i < 4; i++)
#pragma unroll
      for (int j = 0; j < 4; j++)
        acc[i][j] = __builtin_amdgcn_mfma_f32_16x16x32_f16(af[i], bf[j], acc[i][j], 0, 0, 0);
#pragma unroll
    for (int i = 0; i < 4; i++) af[i] = *(const f16x8*)&As[ar + i * 1024 + cb1];
#pragma unroll
    for (int j = 0; j < 4; j++) bf[j] = *(const f16x8*)&Bs[br + j * 1024 + cb1];
#pragma unroll
    for (int i = 0; i < 4; i++)
#pragma unroll
      for (int j = 0; j < 4; j++)
        acc[i][j] = __builtin_amdgcn_mfma_f32_16x16x32_f16(af[i], bf[j], acc[i][j], 0, 0, 0);
  }

  const int cc = l15;
  const int rr = lhi * 4;
  float* Ob = out + (long)bz * SEQ * DIM;
#pragma unroll
  for (int i = 0; i < 4; i++)
#pragma unroll
    for (int r4 = 0; r4 < 4; r4++){
      const int row = bm * 128 + wrow + i * 16 + rr + r4;
      const float inv = 1.f / rowacc[bz * SEQ + row];
#pragma unroll
      for (int j = 0; j < 4; j++){
        const int col = bn * 128 + wcol + j * 16 + cc;
        atomicAdd(&Ob[(long)row * DIM + col], acc[i][j][r4] * inv);
      }
    }
}

extern "C" void kernel_launch(void* const* d_in, const int* in_sizes, int n_in,
                              void* d_out, int out_size, void* d_ws, size_t ws_size,
                              hipStream_t stream){
  const float* x  = (const float*)d_in[0];
  const float* Wq = (const float*)d_in[1];
  const float* bq = (const float*)d_in[2];
  const float* Wk = (const float*)d_in[3];
  const float* bk = (const float*)d_in[4];
  const float* Wv = (const float*)d_in[5];
  const float* bv = (const float*)d_in[6];
  const float* Wo = (const float*)d_in[7];
  const float* bo = (const float*)d_in[8];
  float* out = (float*)d_out;

  char* ws = (char*)d_ws;
  size_t off = 0;
  auto alloc = [&](size_t bytes) -> char* {
    char* p = ws + off; off += (bytes + 255) & ~(size_t)255; return p;
  };

  f16* x16     = (f16*)alloc(2ull * MTOT * DIM);          // 8 MB
  f16* Wcat    = (f16*)alloc(2ull * 3 * DIM * DIM);       // 6 MB  [Wq;Wk;Wv]
  f16* Wo16    = (f16*)alloc(2ull * DIM * DIM);           // 2 MB
  f16* qkcat   = (f16*)alloc(2ull * MTOT * 2 * DIM);      // 16 MB [q|k] per row
  f16* vbuf    = (f16*)alloc(2ull * MTOT * DIM);          // 8 MB  v row-major
  f16* Pbuf    = (f16*)alloc(2ull * NBATCH * SEQ * SEQ);  // 16 MB unnormalized exp
  f16* vWoT    = (f16*)alloc(2ull * NBATCH * DIM * SEQ);  // 8 MB  (v@Wo^T)^T [b][e][t]
  float* rowac = (float*)alloc(4ull * MTOT);              // 16 KB row sums

  if (off > ws_size){
    fill_kernel<<<(out_size + 255) / 256, 256, 0, stream>>>(out, 12345.0f, out_size);
    return;
  }

  // converts + rowacc zero + out = bias prefill
  cvt_all<<<12289, 256, 0, stream>>>(x, Wq, Wk, Wv, Wo, bo,
                                     x16, Wcat, Wo16, rowac, out);

  // fused [q|k|v] = x @ [Wq;Wk;Wv]^T + bias  (grid 32x24 = 768 blocks, 3/CU)
  gemm_qkv<<<dim3(MTOT / 128, 3 * DIM / 128, 1), 256, 0, stream>>>(
      x16, Wcat, qkcat, vbuf, bq, bk, bv);

  // merged: qk->P(+rowsum) [0..511] and vWo^T [512..767], XCD-remapped, 3/CU
  gemm_merged<<<768, 256, 0, stream>>>(qkcat, vbuf, Wo16, Pbuf, vWoT, rowac);

  // out += (P_half @ vWo_half) / rowsum  (split-K=2, 512 blocks = 2/CU)
  gemm_final<<<512, 256, 0, stream>>>(Pbuf, vWoT, out, rowac);
}

// Round 10
// 120.904 us; speedup vs baseline: 1.0662x; 1.0565x over previous
//
#include <hip/hip_runtime.h>
#include <hip/hip_fp16.h>
#include <stdint.h>

typedef _Float16 f16;
typedef __attribute__((ext_vector_type(8))) _Float16 f16x8;
typedef __attribute__((ext_vector_type(4))) _Float16 f16x4;
typedef __attribute__((ext_vector_type(4))) float f32x4;

#define SEQ 2048
#define DIM 1024
#define NBATCH 2
#define MTOT 4096  // NBATCH*SEQ

__global__ void fill_kernel(float* p, float v, int n){
  int i = blockIdx.x * 256 + threadIdx.x;
  if (i < n) p[i] = v;
}

// fp32->fp16 converts: blocks 0..4095 -> x, 4096..8191 -> weights.
__global__ void cvt_all(const float* __restrict__ x, const float* __restrict__ Wq,
                        const float* __restrict__ Wk, const float* __restrict__ Wv,
                        const float* __restrict__ Wo,
                        f16* __restrict__ x16, f16* __restrict__ Wcat, f16* __restrict__ Wo16){
  int b = blockIdx.x;
  const float* src; f16* dst; int i;
  if (b < 4096){
    src = x; dst = x16; i = b * 256 + threadIdx.x;
  } else {
    int t = (b - 4096) >> 10;
    i = ((b - 4096) & 1023) * 256 + threadIdx.x;
    src = t == 0 ? Wq : t == 1 ? Wk : t == 2 ? Wv : Wo;
    dst = (t == 3) ? Wo16 : Wcat + (size_t)t * DIM * DIM;
  }
  float4 v = ((const float4*)src)[i];
  ((f16x4*)dst)[i] = (f16x4){(f16)v.x, (f16)v.y, (f16)v.z, (f16)v.w};
}

#define GLOAD16(SRC, DST) __builtin_amdgcn_global_load_lds( \
    (__attribute__((address_space(1))) void*)(SRC), \
    (__attribute__((address_space(3))) void*)(DST), 16, 0, 0)

// theta -> unnormalized exp (shift 10, clamp 11). x->-inf: e1=inf -> sg=0, th=-1.
__device__ __forceinline__ float theta_exp(float v){
  const float e1 = __expf(-v);
  const float sg = 1.f / (1.f + e1);
  const float e2 = e1 * e1;             // e^{-2x}
  const float th = 2.f / (1.f + e2) - 1.f;
  const float theta = 0.5f + 0.2f * sg + 0.15f * th + 0.1f * fmaxf(v, 0.f);
  return __expf(fminf(theta - 10.f, 11.f));
}

// ---------------------------------------------------------------------------
// qkv: 256-thr 128x128 tile, BK=64, single-buffer, 2 barriers/tile. XOR
// swizzle: LDS[r][cb] = G[r][cb^(r&7)], linear gload_lds dest + pre-swizzled
// source; reads apply same XOR (0 conflicts measured R3-R9). K-loop unrolled
// (NT=16). Grid (32,24) = 768 = 3/CU. ~860 TF measured (shape ceiling).
// ---------------------------------------------------------------------------
__global__ __launch_bounds__(256, 3)
void gemm_qkv(const f16* __restrict__ A0, const f16* __restrict__ B0,
              f16* __restrict__ O0, f16* __restrict__ O1,
              const float* __restrict__ c0, const float* __restrict__ c1,
              const float* __restrict__ c2)
{
  __shared__ __align__(16) f16 As[8192];   // 128 x 64 f16
  __shared__ __align__(16) f16 Bs[8192];
  const int tid  = threadIdx.x;
  const int lane = tid & 63;
  const int wid  = tid >> 6;
  const int bm = blockIdx.x, bn = blockIdx.y;

  const int s_r  = tid >> 3;            // 0..31
  const int s_cb = (tid & 7) ^ (s_r & 7);
  const f16* Ab = A0 + (long)(bm * 128 + s_r) * DIM + s_cb * 8;
  const f16* Bb = B0 + (long)(bn * 128 + s_r) * DIM + s_cb * 8;

  const int l15 = lane & 15, l7 = lane & 7, lhi = lane >> 4;
  const int wrow = (wid >> 1) * 64;
  const int wcol = (wid & 1) * 64;
  const int ar = (wrow + l15) * 64;
  const int br = (wcol + l15) * 64;
  const int cb0 = ((0 + lhi) ^ l7) * 8;
  const int cb1 = ((4 + lhi) ^ l7) * 8;

  f32x4 acc[4][4] = {};

#pragma unroll
  for (int t = 0; t < 16; ++t){
    __syncthreads();
    GLOAD16(Ab + (long)t*64,                  &As[       tid*8]);
    GLOAD16(Ab + (long)t*64 + (long)32 * DIM, &As[2048 + tid*8]);
    GLOAD16(Ab + (long)t*64 + (long)64 * DIM, &As[4096 + tid*8]);
    GLOAD16(Ab + (long)t*64 + (long)96 * DIM, &As[6144 + tid*8]);
    GLOAD16(Bb + (long)t*64,                  &Bs[       tid*8]);
    GLOAD16(Bb + (long)t*64 + (long)32 * DIM, &Bs[2048 + tid*8]);
    GLOAD16(Bb + (long)t*64 + (long)64 * DIM, &Bs[4096 + tid*8]);
    GLOAD16(Bb + (long)t*64 + (long)96 * DIM, &Bs[6144 + tid*8]);
    __syncthreads();
    f16x8 af[4], bf[4];
#pragma unroll
    for (int i = 0; i < 4; i++) af[i] = *(const f16x8*)&As[ar + i * 1024 + cb0];
#pragma unroll
    for (int j = 0; j < 4; j++) bf[j] = *(const f16x8*)&Bs[br + j * 1024 + cb0];
#pragma unroll
    for (int i = 0; i < 4; i++)
#pragma unroll
      for (int j = 0; j < 4; j++)
        acc[i][j] = __builtin_amdgcn_mfma_f32_16x16x32_f16(af[i], bf[j], acc[i][j], 0, 0, 0);
#pragma unroll
    for (int i = 0; i < 4; i++) af[i] = *(const f16x8*)&As[ar + i * 1024 + cb1];
#pragma unroll
    for (int j = 0; j < 4; j++) bf[j] = *(const f16x8*)&Bs[br + j * 1024 + cb1];
#pragma unroll
    for (int i = 0; i < 4; i++)
#pragma unroll
      for (int j = 0; j < 4; j++)
        acc[i][j] = __builtin_amdgcn_mfma_f32_16x16x32_f16(af[i], bf[j], acc[i][j], 0, 0, 0);
  }

  const int cc = l15;
  const int rr = lhi * 4;
#pragma unroll
  for (int i = 0; i < 4; i++)
#pragma unroll
    for (int j = 0; j < 4; j++){
      const int col = bn * 128 + wcol + j * 16 + cc;
      if (col < 2048){
        const float badd = (col < 1024) ? c0[col] : c1[col - 1024];
#pragma unroll
        for (int r = 0; r < 4; r++){
          const int row = bm * 128 + wrow + i * 16 + rr + r;
          O0[(long)row * 2048 + col] = (f16)(acc[i][j][r] + badd);
        }
      } else {
        const int dcol = col - 2048;
        const float badd = c2[dcol];
#pragma unroll
        for (int r = 0; r < 4; r++){
          const int row = bm * 128 + wrow + i * 16 + rr + r;
          O1[(long)row * DIM + dcol] = (f16)(acc[i][j][r] + badd);
        }
      }
    }
}

// ---------------------------------------------------------------------------
// Merged qk + vWo (128x128 tiles, 512 + 256 = 768 blocks, 3/CU), XCD remap
// (r%8 -> XCD heuristic; correctness-independent). NO rowsum here anymore —
// the final kernel computes row sums from its staged P tiles (atomic-free).
//   qk (r<512):   P = theta_exp(q@k^T) -> Pbuf (f16).
//   vWo (r>=512): (v@Wo^T)^T -> vWoT[b][e][t] (f16x4 scatter).
// ---------------------------------------------------------------------------
__global__ __launch_bounds__(256, 3)
void gemm_merged(const f16* __restrict__ qkcat, const f16* __restrict__ vbuf,
                 const f16* __restrict__ Wo16,
                 f16* __restrict__ Pbuf, f16* __restrict__ vWoT)
{
  __shared__ __align__(16) f16 As[8192];
  __shared__ __align__(16) f16 Bs[8192];
  const int tid  = threadIdx.x;
  const int lane = tid & 63;
  const int wid  = tid >> 6;
  const int l15 = lane & 15, l7 = lane & 7, lhi = lane >> 4;
  const int s_r  = tid >> 3;
  const int s_cb = (tid & 7) ^ (s_r & 7);
  const int cb0 = ((0 + lhi) ^ l7) * 8;
  const int cb1 = ((4 + lhi) ^ l7) * 8;
  const int cc = l15, rr = lhi * 4;
  const int wrow = (wid >> 1) * 64;
  const int wcol = (wid & 1) * 64;
  const int ar = (wrow + l15) * 64;
  const int br = (wcol + l15) * 64;
  const int r = blockIdx.x;

  if (r < 512){
    // ---------------- qk path: 128x128, ld 2048 ----------------
    const int x = r & 7, i5 = r >> 3;
    const int bz = x >> 2;
    const int bn = (x & 3) * 4 + (i5 & 3);
    const int bm = i5 >> 2;
    const f16* Ab = qkcat + (long)bz * SEQ * 2048 + (long)(bm * 128 + s_r) * 2048 + s_cb * 8;
    const f16* Bb = qkcat + DIM + (long)bz * SEQ * 2048 + (long)(bn * 128 + s_r) * 2048 + s_cb * 8;

    f32x4 acc[4][4] = {};

#pragma unroll
    for (int t = 0; t < 16; ++t){
      __syncthreads();
      GLOAD16(Ab + (long)t*64,                   &As[       tid*8]);
      GLOAD16(Ab + (long)t*64 + (long)32 * 2048, &As[2048 + tid*8]);
      GLOAD16(Ab + (long)t*64 + (long)64 * 2048, &As[4096 + tid*8]);
      GLOAD16(Ab + (long)t*64 + (long)96 * 2048, &As[6144 + tid*8]);
      GLOAD16(Bb + (long)t*64,                   &Bs[       tid*8]);
      GLOAD16(Bb + (long)t*64 + (long)32 * 2048, &Bs[2048 + tid*8]);
      GLOAD16(Bb + (long)t*64 + (long)64 * 2048, &Bs[4096 + tid*8]);
      GLOAD16(Bb + (long)t*64 + (long)96 * 2048, &Bs[6144 + tid*8]);
      __syncthreads();
      f16x8 af[4], bf[4];
#pragma unroll
      for (int i = 0; i < 4; i++) af[i] = *(const f16x8*)&As[ar + i * 1024 + cb0];
#pragma unroll
      for (int j = 0; j < 4; j++) bf[j] = *(const f16x8*)&Bs[br + j * 1024 + cb0];
#pragma unroll
      for (int i = 0; i < 4; i++)
#pragma unroll
        for (int j = 0; j < 4; j++)
          acc[i][j] = __builtin_amdgcn_mfma_f32_16x16x32_f16(af[i], bf[j], acc[i][j], 0, 0, 0);
#pragma unroll
      for (int i = 0; i < 4; i++) af[i] = *(const f16x8*)&As[ar + i * 1024 + cb1];
#pragma unroll
      for (int j = 0; j < 4; j++) bf[j] = *(const f16x8*)&Bs[br + j * 1024 + cb1];
#pragma unroll
      for (int i = 0; i < 4; i++)
#pragma unroll
        for (int j = 0; j < 4; j++)
          acc[i][j] = __builtin_amdgcn_mfma_f32_16x16x32_f16(af[i], bf[j], acc[i][j], 0, 0, 0);
    }

#pragma unroll
    for (int i = 0; i < 4; i++)
#pragma unroll
      for (int rq = 0; rq < 4; rq++){
        const int row = bm * 128 + wrow + i * 16 + rr + rq;
#pragma unroll
        for (int j = 0; j < 4; j++){
          const int col = bn * 128 + wcol + j * 16 + cc;
          Pbuf[(long)bz * SEQ * SEQ + (long)row * SEQ + col] = (f16)theta_exp(acc[i][j][rq]);
        }
      }
  } else {
    // ---------------- vWo path: 128x128, ld 1024 ----------------
    const int rr2 = r - 512;
    const int x = rr2 & 7, i5 = rr2 >> 3;
    const int bz = x >> 2;
    const int bn = (x & 3) * 2 + (i5 & 1);
    const int bm = i5 >> 1;
    const f16* Ab = vbuf + (long)bz * SEQ * DIM + (long)(bm * 128 + s_r) * DIM + s_cb * 8;
    const f16* Bb = Wo16 + (long)(bn * 128 + s_r) * DIM + s_cb * 8;

    f32x4 acc[4][4] = {};

#pragma unroll
    for (int t = 0; t < 16; ++t){
      __syncthreads();
      GLOAD16(Ab + (long)t*64,                  &As[       tid*8]);
      GLOAD16(Ab + (long)t*64 + (long)32 * DIM, &As[2048 + tid*8]);
      GLOAD16(Ab + (long)t*64 + (long)64 * DIM, &As[4096 + tid*8]);
      GLOAD16(Ab + (long)t*64 + (long)96 * DIM, &As[6144 + tid*8]);
      GLOAD16(Bb + (long)t*64,                  &Bs[       tid*8]);
      GLOAD16(Bb + (long)t*64 + (long)32 * DIM, &Bs[2048 + tid*8]);
      GLOAD16(Bb + (long)t*64 + (long)64 * DIM, &Bs[4096 + tid*8]);
      GLOAD16(Bb + (long)t*64 + (long)96 * DIM, &Bs[6144 + tid*8]);
      __syncthreads();
      f16x8 af[4], bf[4];
#pragma unroll
      for (int i = 0; i < 4; i++) af[i] = *(const f16x8*)&As[ar + i * 1024 + cb0];
#pragma unroll
      for (int j = 0; j < 4; j++) bf[j] = *(const f16x8*)&Bs[br + j * 1024 + cb0];
#pragma unroll
      for (int i = 0; i < 4; i++)
#pragma unroll
        for (int j = 0; j < 4; j++)
          acc[i][j] = __builtin_amdgcn_mfma_f32_16x16x32_f16(af[i], bf[j], acc[i][j], 0, 0, 0);
#pragma unroll
      for (int i = 0; i < 4; i++) af[i] = *(const f16x8*)&As[ar + i * 1024 + cb1];
#pragma unroll
      for (int j = 0; j < 4; j++) bf[j] = *(const f16x8*)&Bs[br + j * 1024 + cb1];
#pragma unroll
      for (int i = 0; i < 4; i++)
#pragma unroll
        for (int j = 0; j < 4; j++)
          acc[i][j] = __builtin_amdgcn_mfma_f32_16x16x32_f16(af[i], bf[j], acc[i][j], 0, 0, 0);
    }

#pragma unroll
    for (int i = 0; i < 4; i++)
#pragma unroll
      for (int j = 0; j < 4; j++){
        const int col = bn * 128 + wcol + j * 16 + cc;       // e
        const int row0 = bm * 128 + wrow + i * 16 + rr;      // t (4 consecutive)
        f16x4 pk = {(f16)acc[i][j][0], (f16)acc[i][j][1],
                    (f16)acc[i][j][2], (f16)acc[i][j][3]};
        *(f16x4*)&vWoT[(long)bz * DIM * SEQ + (long)col * SEQ + row0] = pk;
      }
  }
}

// ---------------------------------------------------------------------------
// Final split-K=2 partials (R8-proven geometry: grid (16,8,4) = 1024 blocks,
// 4/CU, plain stores). psum[kh][b][row][col] fp32.
// NEW: atomic-free row sums. Even waves (wid&1==0) accumulate sum of the af
// P-fragments across the K loop (they cover all 1024 cols of this half for
// rows wrow..wrow+63); 2 shuffles reduce over lhi; bn==0 blocks write
// rowsum[kh*MTOT + gz*SEQ + row]. All 8 bn blocks compute identical sums;
// only bn==0 stores (redundant VALU is free at 7% VALUBusy).
// ---------------------------------------------------------------------------
__global__ __launch_bounds__(256, 4)
void gemm_final(const f16* __restrict__ Pb, const f16* __restrict__ Vw,
                float* __restrict__ psum, float* __restrict__ rowsum)
{
  __shared__ __align__(16) f16 As[8192];
  __shared__ __align__(16) f16 Bs[8192];
  const int tid  = threadIdx.x;
  const int lane = tid & 63;
  const int wid  = tid >> 6;
  const int bm = blockIdx.x, bn = blockIdx.y;
  const int bz = blockIdx.z >> 1, kh = blockIdx.z & 1;

  const f16* Ag = Pb + (long)bz * SEQ * SEQ + (long)kh * 1024;
  const f16* Bg = Vw + (long)bz * DIM * SEQ + (long)kh * 1024;

  const int s_r  = tid >> 3;
  const int s_cb = (tid & 7) ^ (s_r & 7);
  const f16* Ab = Ag + (long)(bm * 128 + s_r) * 2048 + s_cb * 8;
  const f16* Bb = Bg + (long)(bn * 128 + s_r) * 2048 + s_cb * 8;

  const int l15 = lane & 15, l7 = lane & 7, lhi = lane >> 4;
  const int wrow = (wid >> 1) * 64;
  const int wcol = (wid & 1) * 64;
  const int ar = (wrow + l15) * 64;
  const int br = (wcol + l15) * 64;
  const int cb0 = ((0 + lhi) ^ l7) * 8;
  const int cb1 = ((4 + lhi) ^ l7) * 8;
  const bool do_rs = ((wid & 1) == 0);

  f32x4 acc[4][4] = {};
  float rsum[4] = {0.f, 0.f, 0.f, 0.f};

#pragma unroll
  for (int t = 0; t < 16; ++t){
    __syncthreads();
    GLOAD16(Ab + (long)t*64,                   &As[       tid*8]);
    GLOAD16(Ab + (long)t*64 + (long)32 * 2048, &As[2048 + tid*8]);
    GLOAD16(Ab + (long)t*64 + (long)64 * 2048, &As[4096 + tid*8]);
    GLOAD16(Ab + (long)t*64 + (long)96 * 2048, &As[6144 + tid*8]);
    GLOAD16(Bb + (long)t*64,                   &Bs[       tid*8]);
    GLOAD16(Bb + (long)t*64 + (long)32 * 2048, &Bs[2048 + tid*8]);
    GLOAD16(Bb + (long)t*64 + (long)64 * 2048, &Bs[4096 + tid*8]);
    GLOAD16(Bb + (long)t*64 + (long)96 * 2048, &Bs[6144 + tid*8]);
    __syncthreads();
    f16x8 af[4], bf[4];
#pragma unroll
    for (int i = 0; i < 4; i++) af[i] = *(const f16x8*)&As[ar + i * 1024 + cb0];
#pragma unroll
    for (int j = 0; j < 4; j++) bf[j] = *(const f16x8*)&Bs[br + j * 1024 + cb0];
#pragma unroll
    for (int i = 0; i < 4; i++)
#pragma unroll
      for (int j = 0; j < 4; j++)
        acc[i][j] = __builtin_amdgcn_mfma_f32_16x16x32_f16(af[i], bf[j], acc[i][j], 0, 0, 0);
    if (do_rs){
#pragma unroll
      for (int i = 0; i < 4; i++)
#pragma unroll
        for (int e = 0; e < 8; e++) rsum[i] += (float)af[i][e];
    }
#pragma unroll
    for (int i = 0; i < 4; i++) af[i] = *(const f16x8*)&As[ar + i * 1024 + cb1];
#pragma unroll
    for (int j = 0; j < 4; j++) bf[j] = *(const f16x8*)&Bs[br + j * 1024 + cb1];
#pragma unroll
    for (int i = 0; i < 4; i++)
#pragma unroll
      for (int j = 0; j < 4; j++)
        acc[i][j] = __builtin_amdgcn_mfma_f32_16x16x32_f16(af[i], bf[j], acc[i][j], 0, 0, 0);
    if (do_rs){
#pragma unroll
      for (int i = 0; i < 4; i++)
#pragma unroll
        for (int e = 0; e < 8; e++) rsum[i] += (float)af[i][e];
    }
  }

  // row sums: reduce over lhi (4 lanes hold disjoint col chunks of same row)
  if (do_rs){
#pragma unroll
    for (int i = 0; i < 4; i++){
      rsum[i] += __shfl_xor(rsum[i], 16, 64);
      rsum[i] += __shfl_xor(rsum[i], 32, 64);
    }
    if (bn == 0 && lane < 16){
#pragma unroll
      for (int i = 0; i < 4; i++)
        rowsum[(long)kh * MTOT + bz * SEQ + bm * 128 + wrow + i * 16 + lane] = rsum[i];
    }
  }

  const int cc = l15;
  const int rr = lhi * 4;
  float* Po = psum + (long)kh * MTOT * DIM + (long)bz * SEQ * DIM;
#pragma unroll
  for (int i = 0; i < 4; i++)
#pragma unroll
    for (int j = 0; j < 4; j++){
      const int col = bn * 128 + wcol + j * 16 + cc;
#pragma unroll
      for (int r = 0; r < 4; r++){
        const int row = bm * 128 + wrow + i * 16 + rr + r;
        Po[(long)row * DIM + col] = acc[i][j][r];
      }
    }
}

// out = (psum0 + psum1) / (rs0 + rs1) + bo[col], fp32, float4-vectorized.
__global__ __launch_bounds__(256)
void combine_kernel(const float* __restrict__ psum, const float* __restrict__ rowsum,
                    const float* __restrict__ bo, float* __restrict__ out)
{
  const long i = (long)blockIdx.x * 256 + threadIdx.x;   // float4 index
  const int row = (int)(i >> 8);                         // global row 0..4095
  const int c4  = (int)(i & 255);
  float4 a = ((const float4*)psum)[i];
  float4 b = ((const float4*)psum)[i + (long)MTOT * DIM / 4];
  float4 bb = ((const float4*)bo)[c4];
  const float inv = 1.f / (rowsum[row] + rowsum[MTOT + row]);
  float4 o;
  o.x = (a.x + b.x) * inv + bb.x;
  o.y = (a.y + b.y) * inv + bb.y;
  o.z = (a.z + b.z) * inv + bb.z;
  o.w = (a.w + b.w) * inv + bb.w;
  ((float4*)out)[i] = o;
}

extern "C" void kernel_launch(void* const* d_in, const int* in_sizes, int n_in,
                              void* d_out, int out_size, void* d_ws, size_t ws_size,
                              hipStream_t stream){
  const float* x  = (const float*)d_in[0];
  const float* Wq = (const float*)d_in[1];
  const float* bq = (const float*)d_in[2];
  const float* Wk = (const float*)d_in[3];
  const float* bk = (const float*)d_in[4];
  const float* Wv = (const float*)d_in[5];
  const float* bv = (const float*)d_in[6];
  const float* Wo = (const float*)d_in[7];
  const float* bo = (const float*)d_in[8];
  float* out = (float*)d_out;

  char* ws = (char*)d_ws;
  size_t off = 0;
  auto alloc = [&](size_t bytes) -> char* {
    char* p = ws + off; off += (bytes + 255) & ~(size_t)255; return p;
  };

  f16* x16     = (f16*)alloc(2ull * MTOT * DIM);          // 8 MB
  f16* Wcat    = (f16*)alloc(2ull * 3 * DIM * DIM);       // 6 MB  [Wq;Wk;Wv]
  f16* Wo16    = (f16*)alloc(2ull * DIM * DIM);           // 2 MB
  f16* qkcat   = (f16*)alloc(2ull * MTOT * 2 * DIM);      // 16 MB [q|k] per row
  f16* vbuf    = (f16*)alloc(2ull * MTOT * DIM);          // 8 MB  v row-major
  f16* Pbuf    = (f16*)alloc(2ull * NBATCH * SEQ * SEQ);  // 16 MB unnormalized exp
  f16* vWoT    = (f16*)alloc(2ull * NBATCH * DIM * SEQ);  // 8 MB  (v@Wo^T)^T [b][e][t]
  float* psum  = (float*)alloc(4ull * 2 * MTOT * DIM);    // 32 MB split-K partials
  float* rowsm = (float*)alloc(4ull * 2 * MTOT);          // 32 KB partial row sums

  if (off > ws_size){
    fill_kernel<<<(out_size + 255) / 256, 256, 0, stream>>>(out, 12345.0f, out_size);
    return;
  }

  cvt_all<<<8192, 256, 0, stream>>>(x, Wq, Wk, Wv, Wo, x16, Wcat, Wo16);

  // fused [q|k|v] = x @ [Wq;Wk;Wv]^T + bias  (grid 32x24 = 768 blocks, 3/CU)
  gemm_qkv<<<dim3(MTOT / 128, 3 * DIM / 128, 1), 256, 0, stream>>>(
      x16, Wcat, qkcat, vbuf, bq, bk, bv);

  // merged: qk->P [0..511] and vWo^T [512..767], XCD-remapped, 3/CU
  gemm_merged<<<768, 256, 0, stream>>>(qkcat, vbuf, Wo16, Pbuf, vWoT);

  // split-K=2 partials + atomic-free row sums (grid 16x8x4 = 1024 blocks, 4/CU)
  gemm_final<<<dim3(SEQ / 128, DIM / 128, 2 * NBATCH), 256, 0, stream>>>(
      Pbuf, vWoT, psum, rowsm);

  // out = (p0+p1)/(rs0+rs1) + bo  (4096 blocks, float4)
  combine_kernel<<<MTOT * DIM / 4 / 256, 256, 0, stream>>>(psum, rowsm, bo, out);
}